// Round 2
// baseline (754.578 us; speedup 1.0000x reference)
//
#include <hip/hip_runtime.h>
#include <hip/hip_bf16.h>

// SAGE 2-layer: N nodes, E edges, D=256 throughout. All float tensors are
// FP32 in this harness (reference is jnp.float32; threshold 6.406e-3 is
// exactly 2% of max|ref| — dtype-independent). edge_index -> const int*.
//
// Pipeline per call:
//   memset(cnt) -> cast x,W* to bf16 -> count -> scan -> fill(CSR) ->
//   agg1 -> gemm1(+bias+L2norm+relu, bf16 out) ->
//   agg2 -> gemm2(+bias+L2norm, fp32 out to d_out)

#define DD 256

typedef unsigned short ushort_t;
using bf16x8 = __attribute__((ext_vector_type(8))) short;
using f32x4  = __attribute__((ext_vector_type(4))) float;

static __device__ __forceinline__ float b2f(ushort_t u) {
    __hip_bfloat16 h = *reinterpret_cast<__hip_bfloat16*>(&u);
    return __bfloat162float(h);
}
static __device__ __forceinline__ ushort_t f2b(float f) {
    __hip_bfloat16 h = __float2bfloat16(f);
    return *reinterpret_cast<ushort_t*>(&h);
}

// ---------------- fp32 -> bf16 cast ----------------

__global__ void cast_kernel(const float* __restrict__ in, ushort_t* __restrict__ out,
                            int n) {
    int i = (blockIdx.x * 256 + threadIdx.x) * 8;
    if (i + 8 <= n) {
        float4 a = *(const float4*)(in + i);
        float4 b = *(const float4*)(in + i + 4);
        ushort_t o[8] = {f2b(a.x), f2b(a.y), f2b(a.z), f2b(a.w),
                         f2b(b.x), f2b(b.y), f2b(b.z), f2b(b.w)};
        *(int4*)(out + i) = *(const int4*)o;
    } else {
        for (int j = i; j < n; j++) out[j] = f2b(in[j]);
    }
}

// ---------------- CSR build ----------------

__global__ void count_kernel(const int* __restrict__ ei, int* __restrict__ cnt, int E) {
    int e = blockIdx.x * 256 + threadIdx.x;
    if (e < E) atomicAdd(&cnt[ei[E + e]], 1);   // dst row is second row
}

__global__ __launch_bounds__(1024) void scan_kernel(const int* __restrict__ cnt,
                                                    int* __restrict__ offs,
                                                    int* __restrict__ cursor, int n) {
    __shared__ int wtot[16];
    int tid = threadIdx.x;
    int wave = tid >> 6, lane = tid & 63;
    int carry = 0;
    const int CH = 8192;   // 1024 threads x 8 elems
    for (int base = 0; base < n; base += CH) {
        int idx0 = base + tid * 8;
        int v[8], s[8];
        int run = 0;
        #pragma unroll
        for (int j = 0; j < 8; j++) {
            int idx = idx0 + j;
            v[j] = (idx < n) ? cnt[idx] : 0;
            run += v[j];
            s[j] = run;
        }
        int tsum = run;
        int incl = tsum;
        #pragma unroll
        for (int off = 1; off < 64; off <<= 1) {
            int t = __shfl_up(incl, off);
            if (lane >= off) incl += t;
        }
        if (lane == 63) wtot[wave] = incl;
        __syncthreads();
        int woff = 0;
        for (int w = 0; w < wave; w++) woff += wtot[w];
        int chtot = 0;
        for (int w = 0; w < 16; w++) chtot += wtot[w];
        int texcl = carry + woff + (incl - tsum);
        #pragma unroll
        for (int j = 0; j < 8; j++) {
            int idx = idx0 + j;
            if (idx < n) {
                int e = texcl + s[j] - v[j];
                offs[idx] = e;
                cursor[idx] = e;
            }
        }
        carry += chtot;
        __syncthreads();
    }
    if (tid == 0) offs[n] = carry;
}

__global__ void fill_kernel(const int* __restrict__ ei, int* __restrict__ cursor,
                            int* __restrict__ csr, int E) {
    int e = blockIdx.x * 256 + threadIdx.x;
    if (e < E) {
        int s = ei[e];          // src
        int d = ei[E + e];      // dst
        int p = atomicAdd(&cursor[d], 1);
        csr[p] = s;
    }
}

// ---------------- mean aggregation (gather side, bf16 in/out) ----------------

__global__ __launch_bounds__(256) void agg_kernel(const ushort_t* __restrict__ X,
                                                  const int* __restrict__ csr,
                                                  const int* __restrict__ offs,
                                                  ushort_t* __restrict__ mean, int N) {
    int node = blockIdx.x;
    int d = threadIdx.x;
    int beg = offs[node], end = offs[node + 1];
    float acc = 0.f;
    for (int i = beg; i < end; i++) {
        int s = csr[i];
        acc += b2f(X[(size_t)s * DD + d]);
    }
    float mval = acc / fmaxf((float)(end - beg), 1.f);
    mean[(size_t)node * DD + d] = f2b(mval);
}

// ---------------- fused concat-GEMM + bias + L2 norm (+relu) ----------------
// out[n, o] = normalize_row( sum_k mean[n,k] Wl[o,k] + sum_k X[n,k] Wr[o,k] + b[o] )
// Block: 64 rows x 256 cols (full width -> norm fusable). 4 waves, each 64x64.

#define LDA 40   // 32 + 8 pad (keeps 16B alignment, 2-way-max LDS bank aliasing)

__global__ __launch_bounds__(256) void gemm_norm_kernel(
        const ushort_t* __restrict__ A1,   // mean [N,256] bf16
        const ushort_t* __restrict__ A2,   // x or h [N,256] bf16
        const ushort_t* __restrict__ Wl,   // [256,256] row-major bf16
        const ushort_t* __restrict__ Wr,   // [256,256] bf16
        const float*    __restrict__ bias, // [256] fp32
        ushort_t* __restrict__ outb,       // bf16 out (layer 1) or null
        float*    __restrict__ outf,       // fp32 out (layer 2) or null
        int N, int relu) {
    __shared__ ushort_t As[64][LDA];
    __shared__ ushort_t Bs[256][LDA];
    __shared__ float rowsq[64];

    int tid = threadIdx.x;
    int wave = tid >> 6, lane = tid & 63;
    int quad = lane >> 4, m16 = lane & 15;
    int rowbase = blockIdx.x * 64;

    if (tid < 64) rowsq[tid] = 0.f;

    f32x4 acc[4][4];
    #pragma unroll
    for (int i = 0; i < 4; i++)
        #pragma unroll
        for (int j = 0; j < 4; j++)
            acc[i][j] = (f32x4){0.f, 0.f, 0.f, 0.f};

    int arow = tid >> 2;     // 0..63
    int achunk = tid & 3;    // 0..3, 8 bf16 (16B) each
    int brow = tid >> 2;     // o base, +64*i
    int bchunk = tid & 3;

    for (int ki = 0; ki < 16; ki++) {
        int k0 = ki * 32;
        const ushort_t* Aptr;
        const ushort_t* Wptr;
        int koff;
        if (k0 < 256) { Aptr = A1; Wptr = Wl; koff = k0; }
        else          { Aptr = A2; Wptr = Wr; koff = k0 - 256; }

        int4 aval = {0, 0, 0, 0};
        int gr = rowbase + arow;
        if (gr < N)
            aval = *(const int4*)(Aptr + (size_t)gr * DD + koff + achunk * 8);
        int4 bval[4];
        #pragma unroll
        for (int i = 0; i < 4; i++) {
            int o = brow + i * 64;
            bval[i] = *(const int4*)(Wptr + (size_t)o * DD + koff + bchunk * 8);
        }

        __syncthreads();
        *(int4*)(&As[arow][achunk * 8]) = aval;
        #pragma unroll
        for (int i = 0; i < 4; i++)
            *(int4*)(&Bs[brow + i * 64][bchunk * 8]) = bval[i];
        __syncthreads();

        bf16x8 afrag[4], bfrag[4];
        #pragma unroll
        for (int rt = 0; rt < 4; rt++)
            afrag[rt] = *(const bf16x8*)(&As[rt * 16 + m16][quad * 8]);
        #pragma unroll
        for (int ct = 0; ct < 4; ct++)
            bfrag[ct] = *(const bf16x8*)(&Bs[wave * 64 + ct * 16 + m16][quad * 8]);
        #pragma unroll
        for (int rt = 0; rt < 4; rt++)
            #pragma unroll
            for (int ct = 0; ct < 4; ct++)
                acc[rt][ct] = __builtin_amdgcn_mfma_f32_16x16x32_bf16(
                    afrag[rt], bfrag[ct], acc[rt][ct], 0, 0, 0);
    }

    // bias add + per-row sum of squares
    float bvals[4];
    #pragma unroll
    for (int ct = 0; ct < 4; ct++) {
        int col = wave * 64 + ct * 16 + m16;
        bvals[ct] = bias[col];
    }
    #pragma unroll
    for (int rt = 0; rt < 4; rt++) {
        #pragma unroll
        for (int reg = 0; reg < 4; reg++) {
            float s = 0.f;
            #pragma unroll
            for (int ct = 0; ct < 4; ct++) {
                float v = acc[rt][ct][reg] + bvals[ct];
                acc[rt][ct][reg] = v;
                s += v * v;
            }
            // reduce over the 16 lanes (m16) holding this row's 64 wave-cols
            #pragma unroll
            for (int off = 1; off < 16; off <<= 1)
                s += __shfl_xor(s, off);
            if (m16 == 0) {
                int r = rt * 16 + quad * 4 + reg;
                atomicAdd(&rowsq[r], s);
            }
        }
    }
    __syncthreads();

    #pragma unroll
    for (int rt = 0; rt < 4; rt++) {
        #pragma unroll
        for (int reg = 0; reg < 4; reg++) {
            int r = rt * 16 + quad * 4 + reg;
            int gr = rowbase + r;
            if (gr < N) {
                float inv = 1.f / fmaxf(sqrtf(rowsq[r]), 1e-12f);
                #pragma unroll
                for (int ct = 0; ct < 4; ct++) {
                    float v = acc[rt][ct][reg] * inv;
                    if (relu) v = fmaxf(v, 0.f);
                    int col = wave * 64 + ct * 16 + m16;
                    if (outf) outf[(size_t)gr * DD + col] = v;
                    else      outb[(size_t)gr * DD + col] = f2b(v);
                }
            }
        }
    }
}

// ---------------- launch ----------------

static inline size_t align_up(size_t x, size_t a) { return (x + a - 1) & ~(a - 1); }

extern "C" void kernel_launch(void* const* d_in, const int* in_sizes, int n_in,
                              void* d_out, int out_size, void* d_ws, size_t ws_size,
                              hipStream_t stream) {
    const float* x   = (const float*)d_in[0];
    const int*   ei  = (const int*)d_in[1];
    const float* W1l = (const float*)d_in[2];
    const float* b1l = (const float*)d_in[3];
    const float* W1r = (const float*)d_in[4];
    const float* W2l = (const float*)d_in[5];
    const float* b2l = (const float*)d_in[6];
    const float* W2r = (const float*)d_in[7];

    int N = in_sizes[0] / DD;
    int E = in_sizes[1] / 2;
    int NW = DD * DD;   // weight elements

    char* ws = (char*)d_ws;
    size_t off = 0;
    int* cnt = (int*)(ws + off);      off = align_up(off + (size_t)N * 4, 256);
    int* offs = (int*)(ws + off);     off = align_up(off + (size_t)(N + 1) * 4, 256);
    int* cursor = (int*)(ws + off);   off = align_up(off + (size_t)N * 4, 256);
    int* csr = (int*)(ws + off);      off = align_up(off + (size_t)E * 4, 256);
    ushort_t* xb = (ushort_t*)(ws + off);      off = align_up(off + (size_t)N * DD * 2, 256);
    ushort_t* meanbuf = (ushort_t*)(ws + off); off = align_up(off + (size_t)N * DD * 2, 256);
    ushort_t* hb = (ushort_t*)(ws + off);      off = align_up(off + (size_t)N * DD * 2, 256);
    ushort_t* w1lb = (ushort_t*)(ws + off);    off = align_up(off + (size_t)NW * 2, 256);
    ushort_t* w1rb = (ushort_t*)(ws + off);    off = align_up(off + (size_t)NW * 2, 256);
    ushort_t* w2lb = (ushort_t*)(ws + off);    off = align_up(off + (size_t)NW * 2, 256);
    ushort_t* w2rb = (ushort_t*)(ws + off);    off = align_up(off + (size_t)NW * 2, 256);

    hipMemsetAsync(cnt, 0, (size_t)N * 4, stream);

    // casts
    int xe = N * DD;
    cast_kernel<<<(xe / 8 + 255) / 256, 256, 0, stream>>>(x, xb, xe);
    cast_kernel<<<(NW / 8 + 255) / 256, 256, 0, stream>>>(W1l, w1lb, NW);
    cast_kernel<<<(NW / 8 + 255) / 256, 256, 0, stream>>>(W1r, w1rb, NW);
    cast_kernel<<<(NW / 8 + 255) / 256, 256, 0, stream>>>(W2l, w2lb, NW);
    cast_kernel<<<(NW / 8 + 255) / 256, 256, 0, stream>>>(W2r, w2rb, NW);

    int eb = (E + 255) / 256;
    count_kernel<<<eb, 256, 0, stream>>>(ei, cnt, E);
    scan_kernel<<<1, 1024, 0, stream>>>(cnt, offs, cursor, N);
    fill_kernel<<<eb, 256, 0, stream>>>(ei, cursor, csr, E);

    int gb = (N + 63) / 64;

    // layer 1
    agg_kernel<<<N, 256, 0, stream>>>(xb, csr, offs, meanbuf, N);
    gemm_norm_kernel<<<gb, 256, 0, stream>>>(meanbuf, xb, w1lb, w1rb, b1l,
                                             hb, (float*)nullptr, N, 1);

    // layer 2
    agg_kernel<<<N, 256, 0, stream>>>(hb, csr, offs, meanbuf, N);
    gemm_norm_kernel<<<gb, 256, 0, stream>>>(meanbuf, hb, w2lb, w2rb, b2l,
                                             (ushort_t*)nullptr, (float*)d_out, N, 0);
}

// Round 3
// 553.559 us; speedup vs baseline: 1.3631x; 1.3631x over previous
//
#include <hip/hip_runtime.h>
#include <hip/hip_bf16.h>

// SAGE 2-layer: N nodes, E edges, D=256. FP32 inputs, cast to bf16 for MFMA.
// Pipeline: memset(cnt) -> cast x -> cast W*(fused) -> count -> scan -> fill ->
//   agg1 -> gemm1(+bias+L2norm+relu, bf16) -> agg2 -> gemm2(+norm, fp32 out)
//
// R2: agg_kernel was 155us/dispatch, load-issue bound (2B/lane/neighbor).
// Now: 32 threads/node, int4 (8 bf16) per lane per neighbor, 8 nodes/block,
// unroll-by-2 -> 8x fewer load insts, 8 fp32 accumulators of ILP.

#define DD 256

typedef unsigned short ushort_t;
using bf16x8 = __attribute__((ext_vector_type(8))) short;
using f32x4  = __attribute__((ext_vector_type(4))) float;

static __device__ __forceinline__ float b2f(ushort_t u) {
    __hip_bfloat16 h = *reinterpret_cast<__hip_bfloat16*>(&u);
    return __bfloat162float(h);
}
static __device__ __forceinline__ ushort_t f2b(float f) {
    __hip_bfloat16 h = __float2bfloat16(f);
    return *reinterpret_cast<ushort_t*>(&h);
}

// ---------------- fp32 -> bf16 casts ----------------

__global__ void cast_kernel(const float* __restrict__ in, ushort_t* __restrict__ out,
                            int n) {
    int i = (blockIdx.x * 256 + threadIdx.x) * 8;
    if (i + 8 <= n) {
        float4 a = *(const float4*)(in + i);
        float4 b = *(const float4*)(in + i + 4);
        ushort_t o[8] = {f2b(a.x), f2b(a.y), f2b(a.z), f2b(a.w),
                         f2b(b.x), f2b(b.y), f2b(b.z), f2b(b.w)};
        *(int4*)(out + i) = *(const int4*)o;
    } else {
        for (int j = i; j < n; j++) out[j] = f2b(in[j]);
    }
}

// 4 weight matrices in one launch (each n elements, n % 8 == 0)
__global__ void cast4_kernel(const float* __restrict__ i0, const float* __restrict__ i1,
                             const float* __restrict__ i2, const float* __restrict__ i3,
                             ushort_t* __restrict__ o0, ushort_t* __restrict__ o1,
                             ushort_t* __restrict__ o2, ushort_t* __restrict__ o3,
                             int n, int blocks_per) {
    int which = blockIdx.x / blocks_per;
    int blk = blockIdx.x % blocks_per;
    const float* in = (which == 0) ? i0 : (which == 1) ? i1 : (which == 2) ? i2 : i3;
    ushort_t* out = (which == 0) ? o0 : (which == 1) ? o1 : (which == 2) ? o2 : o3;
    int i = (blk * 256 + threadIdx.x) * 8;
    if (i + 8 <= n) {
        float4 a = *(const float4*)(in + i);
        float4 b = *(const float4*)(in + i + 4);
        ushort_t o[8] = {f2b(a.x), f2b(a.y), f2b(a.z), f2b(a.w),
                         f2b(b.x), f2b(b.y), f2b(b.z), f2b(b.w)};
        *(int4*)(out + i) = *(const int4*)o;
    }
}

// ---------------- CSR build ----------------

__global__ void count_kernel(const int* __restrict__ ei, int* __restrict__ cnt, int E) {
    int e = blockIdx.x * 256 + threadIdx.x;
    if (e < E) atomicAdd(&cnt[ei[E + e]], 1);   // dst row is second row
}

__global__ __launch_bounds__(1024) void scan_kernel(const int* __restrict__ cnt,
                                                    int* __restrict__ offs,
                                                    int* __restrict__ cursor, int n) {
    __shared__ int wtot[16];
    int tid = threadIdx.x;
    int wave = tid >> 6, lane = tid & 63;
    int carry = 0;
    const int CH = 8192;   // 1024 threads x 8 elems
    for (int base = 0; base < n; base += CH) {
        int idx0 = base + tid * 8;
        int v[8], s[8];
        int run = 0;
        #pragma unroll
        for (int j = 0; j < 8; j++) {
            int idx = idx0 + j;
            v[j] = (idx < n) ? cnt[idx] : 0;
            run += v[j];
            s[j] = run;
        }
        int tsum = run;
        int incl = tsum;
        #pragma unroll
        for (int off = 1; off < 64; off <<= 1) {
            int t = __shfl_up(incl, off);
            if (lane >= off) incl += t;
        }
        if (lane == 63) wtot[wave] = incl;
        __syncthreads();
        int woff = 0;
        for (int w = 0; w < wave; w++) woff += wtot[w];
        int chtot = 0;
        for (int w = 0; w < 16; w++) chtot += wtot[w];
        int texcl = carry + woff + (incl - tsum);
        #pragma unroll
        for (int j = 0; j < 8; j++) {
            int idx = idx0 + j;
            if (idx < n) {
                int e = texcl + s[j] - v[j];
                offs[idx] = e;
                cursor[idx] = e;
            }
        }
        carry += chtot;
        __syncthreads();
    }
    if (tid == 0) offs[n] = carry;
}

__global__ void fill_kernel(const int* __restrict__ ei, int* __restrict__ cursor,
                            int* __restrict__ csr, int E) {
    int e = blockIdx.x * 256 + threadIdx.x;
    if (e < E) {
        int s = ei[e];          // src
        int d = ei[E + e];      // dst
        int p = atomicAdd(&cursor[d], 1);
        csr[p] = s;
    }
}

// ---------------- mean aggregation (gather, vectorized) ----------------
// 8 nodes per 256-thread block; 32 lanes per node; each lane owns 8 dims
// (one int4 = 8 bf16 per neighbor). Unroll-by-2 for load pipelining.

static __device__ __forceinline__ void add8(float* acc, int4 v) {
    const unsigned* u = (const unsigned*)&v;
    #pragma unroll
    for (int j = 0; j < 4; j++) {
        acc[2 * j]     += __uint_as_float(u[j] << 16);
        acc[2 * j + 1] += __uint_as_float(u[j] & 0xffff0000u);
    }
}

__global__ __launch_bounds__(256) void agg_kernel(const ushort_t* __restrict__ X,
                                                  const int* __restrict__ csr,
                                                  const int* __restrict__ offs,
                                                  ushort_t* __restrict__ mean, int N) {
    int g = threadIdx.x >> 5;           // node group 0..7
    int c = threadIdx.x & 31;           // dim chunk (8 bf16)
    int node = blockIdx.x * 8 + g;
    if (node >= N) return;
    int beg = offs[node], end = offs[node + 1];

    float acc[8];
    #pragma unroll
    for (int j = 0; j < 8; j++) acc[j] = 0.f;

    const ushort_t* base = X + (size_t)c * 8;
    int i = beg;
    for (; i + 2 <= end; i += 2) {
        int s0 = csr[i], s1 = csr[i + 1];
        int4 v0 = *(const int4*)(base + (size_t)s0 * DD);
        int4 v1 = *(const int4*)(base + (size_t)s1 * DD);
        add8(acc, v0);
        add8(acc, v1);
    }
    if (i < end) {
        int s0 = csr[i];
        int4 v0 = *(const int4*)(base + (size_t)s0 * DD);
        add8(acc, v0);
    }

    float scale = 1.f / fmaxf((float)(end - beg), 1.f);
    ushort_t o[8];
    #pragma unroll
    for (int j = 0; j < 8; j++) o[j] = f2b(acc[j] * scale);
    *(int4*)(mean + (size_t)node * DD + c * 8) = *(const int4*)o;
}

// ---------------- fused concat-GEMM + bias + L2 norm (+relu) ----------------
// out[n, o] = normalize_row( sum_k mean[n,k] Wl[o,k] + sum_k X[n,k] Wr[o,k] + b[o] )
// Block: 64 rows x 256 cols (full width -> norm fusable). 4 waves, each 64x64.

#define LDA 40   // 32 + 8 pad (16B-aligned, limits LDS bank aliasing)

__global__ __launch_bounds__(256) void gemm_norm_kernel(
        const ushort_t* __restrict__ A1,   // mean [N,256] bf16
        const ushort_t* __restrict__ A2,   // x or h [N,256] bf16
        const ushort_t* __restrict__ Wl,   // [256,256] row-major bf16
        const ushort_t* __restrict__ Wr,   // [256,256] bf16
        const float*    __restrict__ bias, // [256] fp32
        ushort_t* __restrict__ outb,       // bf16 out (layer 1) or null
        float*    __restrict__ outf,       // fp32 out (layer 2) or null
        int N, int relu) {
    __shared__ ushort_t As[64][LDA];
    __shared__ ushort_t Bs[256][LDA];
    __shared__ float rowsq[64];

    int tid = threadIdx.x;
    int wave = tid >> 6, lane = tid & 63;
    int quad = lane >> 4, m16 = lane & 15;
    int rowbase = blockIdx.x * 64;

    if (tid < 64) rowsq[tid] = 0.f;

    f32x4 acc[4][4];
    #pragma unroll
    for (int i = 0; i < 4; i++)
        #pragma unroll
        for (int j = 0; j < 4; j++)
            acc[i][j] = (f32x4){0.f, 0.f, 0.f, 0.f};

    int arow = tid >> 2;     // 0..63
    int achunk = tid & 3;    // 0..3, 8 bf16 (16B) each
    int brow = tid >> 2;     // o base, +64*i
    int bchunk = tid & 3;

    for (int ki = 0; ki < 16; ki++) {
        int k0 = ki * 32;
        const ushort_t* Aptr;
        const ushort_t* Wptr;
        int koff;
        if (k0 < 256) { Aptr = A1; Wptr = Wl; koff = k0; }
        else          { Aptr = A2; Wptr = Wr; koff = k0 - 256; }

        int4 aval = {0, 0, 0, 0};
        int gr = rowbase + arow;
        if (gr < N)
            aval = *(const int4*)(Aptr + (size_t)gr * DD + koff + achunk * 8);
        int4 bval[4];
        #pragma unroll
        for (int i = 0; i < 4; i++) {
            int o = brow + i * 64;
            bval[i] = *(const int4*)(Wptr + (size_t)o * DD + koff + bchunk * 8);
        }

        __syncthreads();
        *(int4*)(&As[arow][achunk * 8]) = aval;
        #pragma unroll
        for (int i = 0; i < 4; i++)
            *(int4*)(&Bs[brow + i * 64][bchunk * 8]) = bval[i];
        __syncthreads();

        bf16x8 afrag[4], bfrag[4];
        #pragma unroll
        for (int rt = 0; rt < 4; rt++)
            afrag[rt] = *(const bf16x8*)(&As[rt * 16 + m16][quad * 8]);
        #pragma unroll
        for (int ct = 0; ct < 4; ct++)
            bfrag[ct] = *(const bf16x8*)(&Bs[wave * 64 + ct * 16 + m16][quad * 8]);
        #pragma unroll
        for (int rt = 0; rt < 4; rt++)
            #pragma unroll
            for (int ct = 0; ct < 4; ct++)
                acc[rt][ct] = __builtin_amdgcn_mfma_f32_16x16x32_bf16(
                    afrag[rt], bfrag[ct], acc[rt][ct], 0, 0, 0);
    }

    // bias add + per-row sum of squares
    float bvals[4];
    #pragma unroll
    for (int ct = 0; ct < 4; ct++) {
        int col = wave * 64 + ct * 16 + m16;
        bvals[ct] = bias[col];
    }
    #pragma unroll
    for (int rt = 0; rt < 4; rt++) {
        #pragma unroll
        for (int reg = 0; reg < 4; reg++) {
            float s = 0.f;
            #pragma unroll
            for (int ct = 0; ct < 4; ct++) {
                float v = acc[rt][ct][reg] + bvals[ct];
                acc[rt][ct][reg] = v;
                s += v * v;
            }
            #pragma unroll
            for (int off = 1; off < 16; off <<= 1)
                s += __shfl_xor(s, off);
            if (m16 == 0) {
                int r = rt * 16 + quad * 4 + reg;
                atomicAdd(&rowsq[r], s);
            }
        }
    }
    __syncthreads();

    #pragma unroll
    for (int rt = 0; rt < 4; rt++) {
        #pragma unroll
        for (int reg = 0; reg < 4; reg++) {
            int r = rt * 16 + quad * 4 + reg;
            int gr = rowbase + r;
            if (gr < N) {
                float inv = 1.f / fmaxf(sqrtf(rowsq[r]), 1e-12f);
                #pragma unroll
                for (int ct = 0; ct < 4; ct++) {
                    float v = acc[rt][ct][reg] * inv;
                    if (relu) v = fmaxf(v, 0.f);
                    int col = wave * 64 + ct * 16 + m16;
                    if (outf) outf[(size_t)gr * DD + col] = v;
                    else      outb[(size_t)gr * DD + col] = f2b(v);
                }
            }
        }
    }
}

// ---------------- launch ----------------

static inline size_t align_up(size_t x, size_t a) { return (x + a - 1) & ~(a - 1); }

extern "C" void kernel_launch(void* const* d_in, const int* in_sizes, int n_in,
                              void* d_out, int out_size, void* d_ws, size_t ws_size,
                              hipStream_t stream) {
    const float* x   = (const float*)d_in[0];
    const int*   ei  = (const int*)d_in[1];
    const float* W1l = (const float*)d_in[2];
    const float* b1l = (const float*)d_in[3];
    const float* W1r = (const float*)d_in[4];
    const float* W2l = (const float*)d_in[5];
    const float* b2l = (const float*)d_in[6];
    const float* W2r = (const float*)d_in[7];

    int N = in_sizes[0] / DD;
    int E = in_sizes[1] / 2;
    int NW = DD * DD;   // weight elements

    char* ws = (char*)d_ws;
    size_t off = 0;
    int* cnt = (int*)(ws + off);      off = align_up(off + (size_t)N * 4, 256);
    int* offs = (int*)(ws + off);     off = align_up(off + (size_t)(N + 1) * 4, 256);
    int* cursor = (int*)(ws + off);   off = align_up(off + (size_t)N * 4, 256);
    int* csr = (int*)(ws + off);      off = align_up(off + (size_t)E * 4, 256);
    ushort_t* xb = (ushort_t*)(ws + off);      off = align_up(off + (size_t)N * DD * 2, 256);
    ushort_t* meanbuf = (ushort_t*)(ws + off); off = align_up(off + (size_t)N * DD * 2, 256);
    ushort_t* hb = (ushort_t*)(ws + off);      off = align_up(off + (size_t)N * DD * 2, 256);
    ushort_t* w1lb = (ushort_t*)(ws + off);    off = align_up(off + (size_t)NW * 2, 256);
    ushort_t* w1rb = (ushort_t*)(ws + off);    off = align_up(off + (size_t)NW * 2, 256);
    ushort_t* w2lb = (ushort_t*)(ws + off);    off = align_up(off + (size_t)NW * 2, 256);
    ushort_t* w2rb = (ushort_t*)(ws + off);    off = align_up(off + (size_t)NW * 2, 256);

    hipMemsetAsync(cnt, 0, (size_t)N * 4, stream);

    // casts
    int xe = N * DD;
    cast_kernel<<<(xe / 8 + 255) / 256, 256, 0, stream>>>(x, xb, xe);
    int bp = (NW / 8 + 255) / 256;
    cast4_kernel<<<4 * bp, 256, 0, stream>>>(W1l, W1r, W2l, W2r,
                                             w1lb, w1rb, w2lb, w2rb, NW, bp);

    int eb = (E + 255) / 256;
    count_kernel<<<eb, 256, 0, stream>>>(ei, cnt, E);
    scan_kernel<<<1, 1024, 0, stream>>>(cnt, offs, cursor, N);
    fill_kernel<<<eb, 256, 0, stream>>>(ei, cursor, csr, E);

    int gb = (N + 63) / 64;
    int ab = (N + 7) / 8;

    // layer 1
    agg_kernel<<<ab, 256, 0, stream>>>(xb, csr, offs, meanbuf, N);
    gemm_norm_kernel<<<gb, 256, 0, stream>>>(meanbuf, xb, w1lb, w1rb, b1l,
                                             hb, (float*)nullptr, N, 1);

    // layer 2
    agg_kernel<<<ab, 256, 0, stream>>>(hb, csr, offs, meanbuf, N);
    gemm_norm_kernel<<<gb, 256, 0, stream>>>(meanbuf, hb, w2lb, w2rb, b2l,
                                             (ushort_t*)nullptr, (float*)d_out, N, 0);
}

// Round 4
// 444.697 us; speedup vs baseline: 1.6968x; 1.2448x over previous
//
#include <hip/hip_runtime.h>
#include <hip/hip_bf16.h>

// SAGE 2-layer: N nodes, E edges, D=256. FP32 inputs, bf16 MFMA pipeline.
// A-buffer abuf[N,512] = [mean | x] (layer1) then [mean2 | h] (layer2, in place:
// halves never alias across kernels). Combined weights Wc[256 out, 512 k].
//
// R3 gemm was 100us: MfmaUtil 5%, 3.6M LDS conflicts, WRITE_SIZE 95MB (3.7x
// amplification from scattered 2B stores). Now: global_load_lds(16B) staging
// with XOR-swizzled chunks (conflict-free ds_read_b128), BK=64 (32 MFMA per
// barrier pair), epilogue via LDS transpose -> coalesced int4/float4 stores.

#define DD 256

typedef unsigned short ushort_t;
using bf16x8 = __attribute__((ext_vector_type(8))) short;
using f32x4  = __attribute__((ext_vector_type(4))) float;

static __device__ __forceinline__ float b2f(ushort_t u) {
    __hip_bfloat16 h = *reinterpret_cast<__hip_bfloat16*>(&u);
    return __bfloat162float(h);
}
static __device__ __forceinline__ ushort_t f2b(float f) {
    __hip_bfloat16 h = __float2bfloat16(f);
    return *reinterpret_cast<ushort_t*>(&h);
}

static __device__ __forceinline__ void load16(const ushort_t* g, ushort_t* l) {
    __builtin_amdgcn_global_load_lds(
        (const __attribute__((address_space(1))) unsigned*)(g),
        (__attribute__((address_space(3))) unsigned*)(l),
        16, 0, 0);
}

// ---------------- casts (fp32 -> bf16, into combined layouts) ----------------

// x[N,256] -> abuf[:, 256:512]
__global__ void cast_x_kernel(const float* __restrict__ in, ushort_t* __restrict__ abuf,
                              int n) {
    int i = (blockIdx.x * 256 + threadIdx.x) * 8;
    if (i + 8 > n) return;
    int row = i >> 8, col = i & 255;
    float4 a = *(const float4*)(in + i);
    float4 b = *(const float4*)(in + i + 4);
    ushort_t o[8] = {f2b(a.x), f2b(a.y), f2b(a.z), f2b(a.w),
                     f2b(b.x), f2b(b.y), f2b(b.z), f2b(b.w)};
    *(int4*)(abuf + (size_t)row * 512 + 256 + col) = *(const int4*)o;
}

// W1l|W1r -> wc1[256,512], W2l|W2r -> wc2[256,512]
__global__ void cast_w_kernel(const float* __restrict__ w1l, const float* __restrict__ w1r,
                              const float* __restrict__ w2l, const float* __restrict__ w2r,
                              ushort_t* __restrict__ wc1, ushort_t* __restrict__ wc2) {
    int i = (blockIdx.x * 256 + threadIdx.x) * 8;   // 0 .. 4*65536
    int which = i >> 16;            // 0=W1l 1=W1r 2=W2l 3=W2r
    int o = i & 65535;
    int row = o >> 8, col = o & 255;
    const float* src = (which == 0) ? w1l : (which == 1) ? w1r
                      : (which == 2) ? w2l : w2r;
    ushort_t* dst = ((which < 2) ? wc1 : wc2) + (size_t)row * 512 + (which & 1) * 256 + col;
    float4 a = *(const float4*)(src + o);
    float4 b = *(const float4*)(src + o + 4);
    ushort_t ov[8] = {f2b(a.x), f2b(a.y), f2b(a.z), f2b(a.w),
                      f2b(b.x), f2b(b.y), f2b(b.z), f2b(b.w)};
    *(int4*)dst = *(const int4*)ov;
}

// ---------------- CSR build ----------------

__global__ void count_kernel(const int* __restrict__ ei, int* __restrict__ cnt, int E) {
    int e = blockIdx.x * 256 + threadIdx.x;
    if (e < E) atomicAdd(&cnt[ei[E + e]], 1);   // dst row is second row
}

__global__ __launch_bounds__(1024) void scan_kernel(const int* __restrict__ cnt,
                                                    int* __restrict__ offs,
                                                    int* __restrict__ cursor, int n) {
    __shared__ int wtot[16];
    int tid = threadIdx.x;
    int wave = tid >> 6, lane = tid & 63;
    int carry = 0;
    const int CH = 8192;
    for (int base = 0; base < n; base += CH) {
        int idx0 = base + tid * 8;
        int v[8], s[8];
        int run = 0;
        #pragma unroll
        for (int j = 0; j < 8; j++) {
            int idx = idx0 + j;
            v[j] = (idx < n) ? cnt[idx] : 0;
            run += v[j];
            s[j] = run;
        }
        int tsum = run;
        int incl = tsum;
        #pragma unroll
        for (int off = 1; off < 64; off <<= 1) {
            int t = __shfl_up(incl, off);
            if (lane >= off) incl += t;
        }
        if (lane == 63) wtot[wave] = incl;
        __syncthreads();
        int woff = 0;
        for (int w = 0; w < wave; w++) woff += wtot[w];
        int chtot = 0;
        for (int w = 0; w < 16; w++) chtot += wtot[w];
        int texcl = carry + woff + (incl - tsum);
        #pragma unroll
        for (int j = 0; j < 8; j++) {
            int idx = idx0 + j;
            if (idx < n) {
                int e = texcl + s[j] - v[j];
                offs[idx] = e;
                cursor[idx] = e;
            }
        }
        carry += chtot;
        __syncthreads();
    }
    if (tid == 0) offs[n] = carry;
}

__global__ void fill_kernel(const int* __restrict__ ei, int* __restrict__ cursor,
                            int* __restrict__ csr, int E) {
    int e = blockIdx.x * 256 + threadIdx.x;
    if (e < E) {
        int s = ei[e];
        int d = ei[E + e];
        int p = atomicAdd(&cursor[d], 1);
        csr[p] = s;
    }
}

// ---------------- mean aggregation (gather, row stride 512) ----------------
// 8 nodes/block, 32 lanes/node, int4 (8 bf16)/lane/neighbor, unroll-4.

static __device__ __forceinline__ void add8(float* acc, int4 v) {
    const unsigned* u = (const unsigned*)&v;
    #pragma unroll
    for (int j = 0; j < 4; j++) {
        acc[2 * j]     += __uint_as_float(u[j] << 16);
        acc[2 * j + 1] += __uint_as_float(u[j] & 0xffff0000u);
    }
}

__global__ __launch_bounds__(256) void agg_kernel(const ushort_t* __restrict__ X,
                                                  const int* __restrict__ csr,
                                                  const int* __restrict__ offs,
                                                  ushort_t* __restrict__ mean, int N) {
    int g = threadIdx.x >> 5;
    int c = threadIdx.x & 31;
    int node = blockIdx.x * 8 + g;
    if (node >= N) return;
    int beg = offs[node], end = offs[node + 1];

    float acc[8];
    #pragma unroll
    for (int j = 0; j < 8; j++) acc[j] = 0.f;

    const ushort_t* base = X + (size_t)c * 8;
    int i = beg;
    for (; i + 4 <= end; i += 4) {
        int s0 = csr[i], s1 = csr[i + 1], s2 = csr[i + 2], s3 = csr[i + 3];
        int4 v0 = *(const int4*)(base + (size_t)s0 * 512);
        int4 v1 = *(const int4*)(base + (size_t)s1 * 512);
        int4 v2 = *(const int4*)(base + (size_t)s2 * 512);
        int4 v3 = *(const int4*)(base + (size_t)s3 * 512);
        add8(acc, v0); add8(acc, v1); add8(acc, v2); add8(acc, v3);
    }
    for (; i < end; i++) {
        int s0 = csr[i];
        int4 v0 = *(const int4*)(base + (size_t)s0 * 512);
        add8(acc, v0);
    }

    float scale = 1.f / fmaxf((float)(end - beg), 1.f);
    ushort_t o[8];
    #pragma unroll
    for (int j = 0; j < 8; j++) o[j] = f2b(acc[j] * scale);
    *(int4*)(mean + (size_t)node * 512 + c * 8) = *(const int4*)o;
}

// ---------------- fused GEMM + bias + L2 norm (+relu) ----------------
// C[64 rows x 256 cols] per block. A = abuf[N,512], W = wc[256,512].
// BK=64, 8 K-iters. global_load_lds staging, XOR-swizzled 16B chunks:
// LDS physical chunk p of row r holds global chunk p^(r&7) -> both the
// lane-linear DMA constraint and conflict-free ds_read_b128 are satisfied.

__global__ __launch_bounds__(256, 3) void gemm_norm_kernel(
        const ushort_t* __restrict__ abuf,  // [N,512] bf16
        const ushort_t* __restrict__ W,     // [256,512] bf16
        const float*    __restrict__ bias,  // [256] fp32
        ushort_t* __restrict__ outb,        // bf16 out base (pre-offset), or null
        float*    __restrict__ outf,        // fp32 out, or null
        int ostride,                        // out row stride (elements)
        int N, int relu) {
    __shared__ union {
        struct {
            ushort_t As[64 * 64];    // 8 KB
            ushort_t Bs[256 * 64];   // 32 KB
        } s;
        ushort_t ebuf[64 * 264];     // 33.8 KB epilogue transpose buffer
    } u;
    __shared__ float rowsq[64];

    int tid = threadIdx.x;
    int wave = tid >> 6, lane = tid & 63;
    int quad = lane >> 4, m16 = lane & 15;
    int swz = m16 & 7;
    int rowbase = blockIdx.x * 64;

    if (tid < 64) rowsq[tid] = 0.f;

    f32x4 acc[4][4];
    #pragma unroll
    for (int i = 0; i < 4; i++)
        #pragma unroll
        for (int j = 0; j < 4; j++)
            acc[i][j] = (f32x4){0.f, 0.f, 0.f, 0.f};

    const ushort_t* Ag = abuf + (size_t)rowbase * 512;

    for (int ki = 0; ki < 8; ki++) {
        int kb = ki * 64;
        __syncthreads();   // previous iter's LDS reads complete
        // A tile: 64 rows x 64 k = 8 DMA instrs, 2 per wave
        #pragma unroll
        for (int t = 0; t < 2; t++) {
            int instr = wave * 2 + t;
            int flat = instr * 64 + lane;
            int row = flat >> 3, cc = flat & 7;
            int ccg = cc ^ (row & 7);
            load16(Ag + (size_t)row * 512 + kb + ccg * 8, &u.s.As[instr * 512]);
        }
        // B tile: 256 rows x 64 k = 32 DMA instrs, 8 per wave
        #pragma unroll
        for (int t = 0; t < 8; t++) {
            int instr = wave * 8 + t;
            int flat = instr * 64 + lane;
            int row = flat >> 3, cc = flat & 7;
            int ccg = cc ^ (row & 7);
            load16(W + (size_t)row * 512 + kb + ccg * 8, &u.s.Bs[instr * 512]);
        }
        __syncthreads();   // vmcnt(0) drain + barrier: tiles visible

        #pragma unroll
        for (int ks = 0; ks < 2; ks++) {
            int cbase = ks * 4 + quad;
            bf16x8 af[4], bfr[4];
            #pragma unroll
            for (int rt = 0; rt < 4; rt++) {
                int r = rt * 16 + m16;
                af[rt] = *(const bf16x8*)&u.s.As[r * 64 + (cbase ^ swz) * 8];
            }
            #pragma unroll
            for (int ct = 0; ct < 4; ct++) {
                int r = wave * 64 + ct * 16 + m16;
                bfr[ct] = *(const bf16x8*)&u.s.Bs[r * 64 + (cbase ^ swz) * 8];
            }
            #pragma unroll
            for (int rt = 0; rt < 4; rt++)
                #pragma unroll
                for (int ct = 0; ct < 4; ct++)
                    acc[rt][ct] = __builtin_amdgcn_mfma_f32_16x16x32_bf16(
                        af[rt], bfr[ct], acc[rt][ct], 0, 0, 0);
        }
    }

    // bias + per-row sum of squares (C/D layout: col=m16, row=quad*4+reg)
    float bvals[4];
    #pragma unroll
    for (int ct = 0; ct < 4; ct++)
        bvals[ct] = bias[wave * 64 + ct * 16 + m16];
    #pragma unroll
    for (int rt = 0; rt < 4; rt++) {
        #pragma unroll
        for (int reg = 0; reg < 4; reg++) {
            float s = 0.f;
            #pragma unroll
            for (int ct = 0; ct < 4; ct++) {
                float v = acc[rt][ct][reg] + bvals[ct];
                acc[rt][ct][reg] = v;
                s += v * v;
            }
            #pragma unroll
            for (int off = 1; off < 16; off <<= 1)
                s += __shfl_xor(s, off);
            if (m16 == 0)
                atomicAdd(&rowsq[rt * 16 + quad * 4 + reg], s);
        }
    }
    __syncthreads();   // rowsq complete; As/Bs reads done -> ebuf reuse safe

    // normalized values -> ebuf (bf16), then coalesced readback
    #pragma unroll
    for (int rt = 0; rt < 4; rt++) {
        #pragma unroll
        for (int reg = 0; reg < 4; reg++) {
            int r = rt * 16 + quad * 4 + reg;
            float inv = 1.f / fmaxf(sqrtf(rowsq[r]), 1e-12f);
            #pragma unroll
            for (int ct = 0; ct < 4; ct++) {
                float v = acc[rt][ct][reg] * inv;
                if (relu) v = fmaxf(v, 0.f);
                int col = wave * 64 + ct * 16 + m16;
                u.ebuf[r * 264 + col] = f2b(v);
            }
        }
    }
    __syncthreads();

    #pragma unroll
    for (int j = 0; j < 8; j++) {
        int flat = j * 256 + tid;          // 2048 chunks = 64 rows x 32
        int row = flat >> 5, cc = flat & 31;
        int gr = rowbase + row;
        if (gr < N) {
            bf16x8 v = *(const bf16x8*)&u.ebuf[row * 264 + cc * 8];
            if (outf) {
                float4 f0, f1;
                f0.x = b2f((ushort_t)v[0]); f0.y = b2f((ushort_t)v[1]);
                f0.z = b2f((ushort_t)v[2]); f0.w = b2f((ushort_t)v[3]);
                f1.x = b2f((ushort_t)v[4]); f1.y = b2f((ushort_t)v[5]);
                f1.z = b2f((ushort_t)v[6]); f1.w = b2f((ushort_t)v[7]);
                float* p = outf + (size_t)gr * ostride + cc * 8;
                *(float4*)p = f0;
                *(float4*)(p + 4) = f1;
            } else {
                *(bf16x8*)(outb + (size_t)gr * ostride + cc * 8) = v;
            }
        }
    }
}

// ---------------- launch ----------------

static inline size_t align_up(size_t x, size_t a) { return (x + a - 1) & ~(a - 1); }

extern "C" void kernel_launch(void* const* d_in, const int* in_sizes, int n_in,
                              void* d_out, int out_size, void* d_ws, size_t ws_size,
                              hipStream_t stream) {
    const float* x   = (const float*)d_in[0];
    const int*   ei  = (const int*)d_in[1];
    const float* W1l = (const float*)d_in[2];
    const float* b1l = (const float*)d_in[3];
    const float* W1r = (const float*)d_in[4];
    const float* W2l = (const float*)d_in[5];
    const float* b2l = (const float*)d_in[6];
    const float* W2r = (const float*)d_in[7];

    int N = in_sizes[0] / DD;
    int E = in_sizes[1] / 2;

    char* ws = (char*)d_ws;
    size_t off = 0;
    int* cnt = (int*)(ws + off);      off = align_up(off + (size_t)N * 4, 256);
    int* offs = (int*)(ws + off);     off = align_up(off + (size_t)(N + 1) * 4, 256);
    int* cursor = (int*)(ws + off);   off = align_up(off + (size_t)N * 4, 256);
    int* csr = (int*)(ws + off);      off = align_up(off + (size_t)E * 4, 256);
    ushort_t* abuf = (ushort_t*)(ws + off);  off = align_up(off + (size_t)N * 512 * 2, 256);
    // gemm A-tile overreads up to 48 rows past N: wc1/wc2 (512KB) provide slack
    ushort_t* wc1 = (ushort_t*)(ws + off);   off = align_up(off + (size_t)256 * 512 * 2, 256);
    ushort_t* wc2 = (ushort_t*)(ws + off);   off = align_up(off + (size_t)256 * 512 * 2, 256);

    hipMemsetAsync(cnt, 0, (size_t)N * 4, stream);

    int xe = N * DD;
    cast_x_kernel<<<(xe / 8 + 255) / 256, 256, 0, stream>>>(x, abuf, xe);
    cast_w_kernel<<<(4 * DD * DD / 8) / 256, 256, 0, stream>>>(W1l, W1r, W2l, W2r,
                                                               wc1, wc2);

    int eb = (E + 255) / 256;
    count_kernel<<<eb, 256, 0, stream>>>(ei, cnt, E);
    scan_kernel<<<1, 1024, 0, stream>>>(cnt, offs, cursor, N);
    fill_kernel<<<eb, 256, 0, stream>>>(ei, cursor, csr, E);

    int gb = (N + 63) / 64;
    int ab = (N + 7) / 8;

    // layer 1: agg x -> abuf[:,0:256]; gemm -> h into abuf[:,256:512] (bf16)
    agg_kernel<<<ab, 256, 0, stream>>>(abuf + 256, csr, offs, abuf, N);
    gemm_norm_kernel<<<gb, 256, 0, stream>>>(abuf, wc1, b1l,
                                             abuf + 256, (float*)nullptr, 512, N, 1);

    // layer 2: agg h -> abuf[:,0:256]; gemm -> d_out (fp32)
    agg_kernel<<<ab, 256, 0, stream>>>(abuf + 256, csr, offs, abuf, N);
    gemm_norm_kernel<<<gb, 256, 0, stream>>>(abuf, wc2, b2l,
                                             (ushort_t*)nullptr, (float*)d_out, DD, N, 0);
}

// Round 5
// 378.691 us; speedup vs baseline: 1.9926x; 1.1743x over previous
//
#include <hip/hip_runtime.h>
#include <hip/hip_bf16.h>

// SAGE 2-layer: N nodes, E edges, D=256. FP32 inputs, bf16 MFMA pipeline.
// A-buffer abuf[N,512] = [mean | x] (layer1) then [mean2 | h] (layer2, in place).
// Combined weights Wc[256 out, 512 k].
//
// R4: single-block scan_kernel was the top dispatch (68.6us, one CU,
// latency-bound). Now a 3-stage device-wide scan: partials(25 blocks) ->
// 1-wave partial scan -> local rescan+base. offs[N]=E statically.

#define DD 256

typedef unsigned short ushort_t;
using bf16x8 = __attribute__((ext_vector_type(8))) short;
using f32x4  = __attribute__((ext_vector_type(4))) float;

static __device__ __forceinline__ float b2f(ushort_t u) {
    __hip_bfloat16 h = *reinterpret_cast<__hip_bfloat16*>(&u);
    return __bfloat162float(h);
}
static __device__ __forceinline__ ushort_t f2b(float f) {
    __hip_bfloat16 h = __float2bfloat16(f);
    return *reinterpret_cast<ushort_t*>(&h);
}

static __device__ __forceinline__ void load16(const ushort_t* g, ushort_t* l) {
    __builtin_amdgcn_global_load_lds(
        (const __attribute__((address_space(1))) unsigned*)(g),
        (__attribute__((address_space(3))) unsigned*)(l),
        16, 0, 0);
}

// ---------------- casts (fp32 -> bf16, into combined layouts) ----------------

// x[N,256] -> abuf[:, 256:512]
__global__ void cast_x_kernel(const float* __restrict__ in, ushort_t* __restrict__ abuf,
                              int n) {
    int i = (blockIdx.x * 256 + threadIdx.x) * 8;
    if (i + 8 > n) return;
    int row = i >> 8, col = i & 255;
    float4 a = *(const float4*)(in + i);
    float4 b = *(const float4*)(in + i + 4);
    ushort_t o[8] = {f2b(a.x), f2b(a.y), f2b(a.z), f2b(a.w),
                     f2b(b.x), f2b(b.y), f2b(b.z), f2b(b.w)};
    *(int4*)(abuf + (size_t)row * 512 + 256 + col) = *(const int4*)o;
}

// W1l|W1r -> wc1[256,512], W2l|W2r -> wc2[256,512]
__global__ void cast_w_kernel(const float* __restrict__ w1l, const float* __restrict__ w1r,
                              const float* __restrict__ w2l, const float* __restrict__ w2r,
                              ushort_t* __restrict__ wc1, ushort_t* __restrict__ wc2) {
    int i = (blockIdx.x * 256 + threadIdx.x) * 8;   // 0 .. 4*65536
    int which = i >> 16;            // 0=W1l 1=W1r 2=W2l 3=W2r
    int o = i & 65535;
    int row = o >> 8, col = o & 255;
    const float* src = (which == 0) ? w1l : (which == 1) ? w1r
                      : (which == 2) ? w2l : w2r;
    ushort_t* dst = ((which < 2) ? wc1 : wc2) + (size_t)row * 512 + (which & 1) * 256 + col;
    float4 a = *(const float4*)(src + o);
    float4 b = *(const float4*)(src + o + 4);
    ushort_t ov[8] = {f2b(a.x), f2b(a.y), f2b(a.z), f2b(a.w),
                      f2b(b.x), f2b(b.y), f2b(b.z), f2b(b.w)};
    *(int4*)dst = *(const int4*)ov;
}

// ---------------- CSR build ----------------

__global__ void count_kernel(const int* __restrict__ ei, int* __restrict__ cnt, int E) {
    int e = blockIdx.x * 256 + threadIdx.x;
    if (e < E) atomicAdd(&cnt[ei[E + e]], 1);   // dst row is second row
}

// Stage 1: per-block (2048 elems) sums.
__global__ __launch_bounds__(256) void scan_partial_kernel(const int* __restrict__ cnt,
                                                           int* __restrict__ part, int n) {
    __shared__ int ws[4];
    int tid = threadIdx.x;
    int wave = tid >> 6, lane = tid & 63;
    int i0 = blockIdx.x * 2048 + tid * 8;
    int sum = 0;
    if (i0 + 8 <= n) {
        int4 a = *(const int4*)(cnt + i0);
        int4 b = *(const int4*)(cnt + i0 + 4);
        sum = a.x + a.y + a.z + a.w + b.x + b.y + b.z + b.w;
    } else {
        for (int j = i0; j < n; j++) sum += cnt[j];
    }
    #pragma unroll
    for (int off = 1; off < 64; off <<= 1) sum += __shfl_xor(sum, off);
    if (lane == 0) ws[wave] = sum;
    __syncthreads();
    if (tid == 0) part[blockIdx.x] = ws[0] + ws[1] + ws[2] + ws[3];
}

// Stage 2: exclusive scan of partials (single wave; nb <= 64).
__global__ void scan_partials2_kernel(int* __restrict__ part, int nb) {
    int lane = threadIdx.x;
    int v = (lane < nb) ? part[lane] : 0;
    int orig = v;
    #pragma unroll
    for (int off = 1; off < 64; off <<= 1) {
        int t = __shfl_up(v, off);
        if (lane >= off) v += t;
    }
    if (lane < nb) part[lane] = v - orig;   // exclusive base
}

// Stage 3: local rescan + base -> offs/cursor. offs[n] = E (degree sum).
__global__ __launch_bounds__(256) void scan_final_kernel(const int* __restrict__ cnt,
                                                         const int* __restrict__ part,
                                                         int* __restrict__ offs,
                                                         int* __restrict__ cursor,
                                                         int n, int E) {
    __shared__ int wt[4];
    int tid = threadIdx.x;
    int wave = tid >> 6, lane = tid & 63;
    int i0 = blockIdx.x * 2048 + tid * 8;
    int v[8], s[8];
    int run = 0;
    if (i0 + 8 <= n) {
        int4 a = *(const int4*)(cnt + i0);
        int4 b = *(const int4*)(cnt + i0 + 4);
        v[0] = a.x; v[1] = a.y; v[2] = a.z; v[3] = a.w;
        v[4] = b.x; v[5] = b.y; v[6] = b.z; v[7] = b.w;
    } else {
        #pragma unroll
        for (int j = 0; j < 8; j++) v[j] = (i0 + j < n) ? cnt[i0 + j] : 0;
    }
    #pragma unroll
    for (int j = 0; j < 8; j++) { run += v[j]; s[j] = run; }
    int tsum = run;
    int incl = tsum;
    #pragma unroll
    for (int off = 1; off < 64; off <<= 1) {
        int t = __shfl_up(incl, off);
        if (lane >= off) incl += t;
    }
    if (lane == 63) wt[wave] = incl;
    __syncthreads();
    int woff = 0;
    for (int w = 0; w < wave; w++) woff += wt[w];
    int texcl = part[blockIdx.x] + woff + (incl - tsum);
    #pragma unroll
    for (int j = 0; j < 8; j++) {
        int idx = i0 + j;
        if (idx < n) {
            int e = texcl + s[j] - v[j];
            offs[idx] = e;
            cursor[idx] = e;
        }
    }
    if (blockIdx.x == 0 && tid == 0) offs[n] = E;
}

__global__ void fill_kernel(const int* __restrict__ ei, int* __restrict__ cursor,
                            int* __restrict__ csr, int E) {
    int e = blockIdx.x * 256 + threadIdx.x;
    if (e < E) {
        int s = ei[e];
        int d = ei[E + e];
        int p = atomicAdd(&cursor[d], 1);
        csr[p] = s;
    }
}

// ---------------- mean aggregation (gather, row stride 512) ----------------
// 8 nodes/block, 32 lanes/node, int4 (8 bf16)/lane/neighbor, unroll-4.

static __device__ __forceinline__ void add8(float* acc, int4 v) {
    const unsigned* u = (const unsigned*)&v;
    #pragma unroll
    for (int j = 0; j < 4; j++) {
        acc[2 * j]     += __uint_as_float(u[j] << 16);
        acc[2 * j + 1] += __uint_as_float(u[j] & 0xffff0000u);
    }
}

__global__ __launch_bounds__(256) void agg_kernel(const ushort_t* __restrict__ X,
                                                  const int* __restrict__ csr,
                                                  const int* __restrict__ offs,
                                                  ushort_t* __restrict__ mean, int N) {
    int g = threadIdx.x >> 5;
    int c = threadIdx.x & 31;
    int node = blockIdx.x * 8 + g;
    if (node >= N) return;
    int beg = offs[node], end = offs[node + 1];

    float acc[8];
    #pragma unroll
    for (int j = 0; j < 8; j++) acc[j] = 0.f;

    const ushort_t* base = X + (size_t)c * 8;
    int i = beg;
    for (; i + 4 <= end; i += 4) {
        int s0 = csr[i], s1 = csr[i + 1], s2 = csr[i + 2], s3 = csr[i + 3];
        int4 v0 = *(const int4*)(base + (size_t)s0 * 512);
        int4 v1 = *(const int4*)(base + (size_t)s1 * 512);
        int4 v2 = *(const int4*)(base + (size_t)s2 * 512);
        int4 v3 = *(const int4*)(base + (size_t)s3 * 512);
        add8(acc, v0); add8(acc, v1); add8(acc, v2); add8(acc, v3);
    }
    for (; i < end; i++) {
        int s0 = csr[i];
        int4 v0 = *(const int4*)(base + (size_t)s0 * 512);
        add8(acc, v0);
    }

    float scale = 1.f / fmaxf((float)(end - beg), 1.f);
    ushort_t o[8];
    #pragma unroll
    for (int j = 0; j < 8; j++) o[j] = f2b(acc[j] * scale);
    *(int4*)(mean + (size_t)node * 512 + c * 8) = *(const int4*)o;
}

// ---------------- fused GEMM + bias + L2 norm (+relu) ----------------
// C[64 rows x 256 cols] per block. A = abuf[N,512], W = wc[256,512].
// BK=64, 8 K-iters. global_load_lds staging, XOR-swizzled 16B chunks.

__global__ __launch_bounds__(256, 3) void gemm_norm_kernel(
        const ushort_t* __restrict__ abuf,  // [N,512] bf16
        const ushort_t* __restrict__ W,     // [256,512] bf16
        const float*    __restrict__ bias,  // [256] fp32
        ushort_t* __restrict__ outb,        // bf16 out base (pre-offset), or null
        float*    __restrict__ outf,        // fp32 out, or null
        int ostride,                        // out row stride (elements)
        int N, int relu) {
    __shared__ union {
        struct {
            ushort_t As[64 * 64];    // 8 KB
            ushort_t Bs[256 * 64];   // 32 KB
        } s;
        ushort_t ebuf[64 * 264];     // 33.8 KB epilogue transpose buffer
    } u;
    __shared__ float rowsq[64];

    int tid = threadIdx.x;
    int wave = tid >> 6, lane = tid & 63;
    int quad = lane >> 4, m16 = lane & 15;
    int swz = m16 & 7;
    int rowbase = blockIdx.x * 64;

    if (tid < 64) rowsq[tid] = 0.f;

    f32x4 acc[4][4];
    #pragma unroll
    for (int i = 0; i < 4; i++)
        #pragma unroll
        for (int j = 0; j < 4; j++)
            acc[i][j] = (f32x4){0.f, 0.f, 0.f, 0.f};

    const ushort_t* Ag = abuf + (size_t)rowbase * 512;

    for (int ki = 0; ki < 8; ki++) {
        int kb = ki * 64;
        __syncthreads();   // previous iter's LDS reads complete
        #pragma unroll
        for (int t = 0; t < 2; t++) {
            int instr = wave * 2 + t;
            int flat = instr * 64 + lane;
            int row = flat >> 3, cc = flat & 7;
            int ccg = cc ^ (row & 7);
            load16(Ag + (size_t)row * 512 + kb + ccg * 8, &u.s.As[instr * 512]);
        }
        #pragma unroll
        for (int t = 0; t < 8; t++) {
            int instr = wave * 8 + t;
            int flat = instr * 64 + lane;
            int row = flat >> 3, cc = flat & 7;
            int ccg = cc ^ (row & 7);
            load16(W + (size_t)row * 512 + kb + ccg * 8, &u.s.Bs[instr * 512]);
        }
        __syncthreads();   // vmcnt(0) drain + barrier: tiles visible

        #pragma unroll
        for (int ks = 0; ks < 2; ks++) {
            int cbase = ks * 4 + quad;
            bf16x8 af[4], bfr[4];
            #pragma unroll
            for (int rt = 0; rt < 4; rt++) {
                int r = rt * 16 + m16;
                af[rt] = *(const bf16x8*)&u.s.As[r * 64 + (cbase ^ swz) * 8];
            }
            #pragma unroll
            for (int ct = 0; ct < 4; ct++) {
                int r = wave * 64 + ct * 16 + m16;
                bfr[ct] = *(const bf16x8*)&u.s.Bs[r * 64 + (cbase ^ swz) * 8];
            }
            #pragma unroll
            for (int rt = 0; rt < 4; rt++)
                #pragma unroll
                for (int ct = 0; ct < 4; ct++)
                    acc[rt][ct] = __builtin_amdgcn_mfma_f32_16x16x32_bf16(
                        af[rt], bfr[ct], acc[rt][ct], 0, 0, 0);
        }
    }

    // bias + per-row sum of squares (C/D layout: col=m16, row=quad*4+reg)
    float bvals[4];
    #pragma unroll
    for (int ct = 0; ct < 4; ct++)
        bvals[ct] = bias[wave * 64 + ct * 16 + m16];
    #pragma unroll
    for (int rt = 0; rt < 4; rt++) {
        #pragma unroll
        for (int reg = 0; reg < 4; reg++) {
            float s = 0.f;
            #pragma unroll
            for (int ct = 0; ct < 4; ct++) {
                float v = acc[rt][ct][reg] + bvals[ct];
                acc[rt][ct][reg] = v;
                s += v * v;
            }
            #pragma unroll
            for (int off = 1; off < 16; off <<= 1)
                s += __shfl_xor(s, off);
            if (m16 == 0)
                atomicAdd(&rowsq[rt * 16 + quad * 4 + reg], s);
        }
    }
    __syncthreads();   // rowsq complete; As/Bs reads done -> ebuf reuse safe

    // normalized values -> ebuf (bf16), then coalesced readback
    #pragma unroll
    for (int rt = 0; rt < 4; rt++) {
        #pragma unroll
        for (int reg = 0; reg < 4; reg++) {
            int r = rt * 16 + quad * 4 + reg;
            float inv = 1.f / fmaxf(sqrtf(rowsq[r]), 1e-12f);
            #pragma unroll
            for (int ct = 0; ct < 4; ct++) {
                float v = acc[rt][ct][reg] * inv;
                if (relu) v = fmaxf(v, 0.f);
                int col = wave * 64 + ct * 16 + m16;
                u.ebuf[r * 264 + col] = f2b(v);
            }
        }
    }
    __syncthreads();

    #pragma unroll
    for (int j = 0; j < 8; j++) {
        int flat = j * 256 + tid;          // 2048 chunks = 64 rows x 32
        int row = flat >> 5, cc = flat & 31;
        int gr = rowbase + row;
        if (gr < N) {
            bf16x8 v = *(const bf16x8*)&u.ebuf[row * 264 + cc * 8];
            if (outf) {
                float4 f0, f1;
                f0.x = b2f((ushort_t)v[0]); f0.y = b2f((ushort_t)v[1]);
                f0.z = b2f((ushort_t)v[2]); f0.w = b2f((ushort_t)v[3]);
                f1.x = b2f((ushort_t)v[4]); f1.y = b2f((ushort_t)v[5]);
                f1.z = b2f((ushort_t)v[6]); f1.w = b2f((ushort_t)v[7]);
                float* p = outf + (size_t)gr * ostride + cc * 8;
                *(float4*)p = f0;
                *(float4*)(p + 4) = f1;
            } else {
                *(bf16x8*)(outb + (size_t)gr * ostride + cc * 8) = v;
            }
        }
    }
}

// ---------------- launch ----------------

static inline size_t align_up(size_t x, size_t a) { return (x + a - 1) & ~(a - 1); }

extern "C" void kernel_launch(void* const* d_in, const int* in_sizes, int n_in,
                              void* d_out, int out_size, void* d_ws, size_t ws_size,
                              hipStream_t stream) {
    const float* x   = (const float*)d_in[0];
    const int*   ei  = (const int*)d_in[1];
    const float* W1l = (const float*)d_in[2];
    const float* b1l = (const float*)d_in[3];
    const float* W1r = (const float*)d_in[4];
    const float* W2l = (const float*)d_in[5];
    const float* b2l = (const float*)d_in[6];
    const float* W2r = (const float*)d_in[7];

    int N = in_sizes[0] / DD;
    int E = in_sizes[1] / 2;

    char* ws = (char*)d_ws;
    size_t off = 0;
    int* cnt = (int*)(ws + off);      off = align_up(off + (size_t)N * 4, 256);
    int* offs = (int*)(ws + off);     off = align_up(off + (size_t)(N + 1) * 4, 256);
    int* cursor = (int*)(ws + off);   off = align_up(off + (size_t)N * 4, 256);
    int* part = (int*)(ws + off);     off = align_up(off + (size_t)64 * 4, 256);
    int* csr = (int*)(ws + off);      off = align_up(off + (size_t)E * 4, 256);
    ushort_t* abuf = (ushort_t*)(ws + off);  off = align_up(off + (size_t)N * 512 * 2, 256);
    // gemm A-tile overreads up to 48 rows past N: wc1/wc2 (512KB) provide slack
    ushort_t* wc1 = (ushort_t*)(ws + off);   off = align_up(off + (size_t)256 * 512 * 2, 256);
    ushort_t* wc2 = (ushort_t*)(ws + off);   off = align_up(off + (size_t)256 * 512 * 2, 256);

    hipMemsetAsync(cnt, 0, (size_t)N * 4, stream);

    int xe = N * DD;
    cast_x_kernel<<<(xe / 8 + 255) / 256, 256, 0, stream>>>(x, abuf, xe);
    cast_w_kernel<<<(4 * DD * DD / 8) / 256, 256, 0, stream>>>(W1l, W1r, W2l, W2r,
                                                               wc1, wc2);

    int eb = (E + 255) / 256;
    count_kernel<<<eb, 256, 0, stream>>>(ei, cnt, E);
    int nb = (N + 2047) / 2048;   // <= 64 for N <= 131072
    scan_partial_kernel<<<nb, 256, 0, stream>>>(cnt, part, N);
    scan_partials2_kernel<<<1, 64, 0, stream>>>(part, nb);
    scan_final_kernel<<<nb, 256, 0, stream>>>(cnt, part, offs, cursor, N, E);
    fill_kernel<<<eb, 256, 0, stream>>>(ei, cursor, csr, E);

    int gb = (N + 63) / 64;
    int ab = (N + 7) / 8;

    // layer 1: agg x -> abuf[:,0:256]; gemm -> h into abuf[:,256:512] (bf16)
    agg_kernel<<<ab, 256, 0, stream>>>(abuf + 256, csr, offs, abuf, N);
    gemm_norm_kernel<<<gb, 256, 0, stream>>>(abuf, wc1, b1l,
                                             abuf + 256, (float*)nullptr, 512, N, 1);

    // layer 2: agg h -> abuf[:,0:256]; gemm -> d_out (fp32)
    agg_kernel<<<ab, 256, 0, stream>>>(abuf + 256, csr, offs, abuf, N);
    gemm_norm_kernel<<<gb, 256, 0, stream>>>(abuf, wc2, b2l,
                                             (ushort_t*)nullptr, (float*)d_out, DD, N, 0);
}